// Round 1
// baseline (392.569 us; speedup 1.0000x reference)
//
#include <hip/hip_runtime.h>
#include <hip/hip_bf16.h>

typedef __attribute__((ext_vector_type(8))) short bf16x8;
typedef __attribute__((ext_vector_type(4))) float f32x4;

#define LOG2E  1.4426950408889634f
#define QSCALE 0.08838834764831845f   // 1/sqrt(128)

// LDS row strides (in shorts)
#define KLD 136   // 128 + 8 pad -> 272 B rows, 16B aligned, ~2-way banks
#define VLD 72    // 64 + 8 pad  -> 144 B rows, 16B aligned
#define PLD 72

__device__ __forceinline__ short f2bf(float f) {
  union { float f; unsigned u; } x;
  x.f = f;
  unsigned u = x.u;
  u += 0x7fffu + ((u >> 16) & 1u);   // RNE
  return (short)(u >> 16);
}

__global__ __launch_bounds__(256, 2) void attn_fwd(
    const float* __restrict__ Qg, const float* __restrict__ Kg,
    const float* __restrict__ Vg, float* __restrict__ Og)
{
  __shared__ short K_lds[64 * KLD];        // K tile, row-major [kv][d]
  __shared__ short V_T[128 * VLD];         // V tile, transposed [d][kv]
  __shared__ short P_lds[4][2 * 16 * PLD]; // per-wave P buffer [mt*16+row][kv]

  const int tid  = threadIdx.x;
  const int lane = tid & 63;
  const int wave = tid >> 6;
  const int g    = lane >> 4;   // 0..3
  const int lo   = lane & 15;   // 0..15

  const int bh = blockIdx.x;    // 0..63  (head fastest -> balanced causal load)
  const int qt = blockIdx.y;    // 0..15
  const int q0 = qt * 128;

  const size_t base = (size_t)bh * 2048 * 128;
  const float* Qb = Qg + base;
  const float* Kb = Kg + base;
  const float* Vb = Vg + base;
  float*       Ob = Og + base;

  // --- load Q fragments (scaled by 1/sqrt(D)), A-layout: row=lo, k=g*8+j ---
  bf16x8 qf[2][4];
  #pragma unroll
  for (int mt = 0; mt < 2; ++mt) {
    const int row = q0 + wave * 32 + mt * 16 + lo;
    const float* qr = Qb + (size_t)row * 128 + g * 8;
    #pragma unroll
    for (int kb = 0; kb < 4; ++kb) {
      f32x4 a = *(const f32x4*)(qr + kb * 32);
      f32x4 b = *(const f32x4*)(qr + kb * 32 + 4);
      bf16x8 w;
      #pragma unroll
      for (int j = 0; j < 4; ++j) { w[j] = f2bf(a[j] * QSCALE); w[4 + j] = f2bf(b[j] * QSCALE); }
      qf[mt][kb] = w;
    }
  }

  float m_st[2][4], l_st[2][4];
  f32x4 o_acc[2][8];
  #pragma unroll
  for (int mt = 0; mt < 2; ++mt) {
    #pragma unroll
    for (int r = 0; r < 4; ++r) { m_st[mt][r] = -3.0e38f; l_st[mt][r] = 0.0f; }
    #pragma unroll
    for (int nb = 0; nb < 8; ++nb) o_acc[mt][nb] = (f32x4){0.f, 0.f, 0.f, 0.f};
  }

  short* Pw = P_lds[wave];

  const int kv_end = q0 + 128;   // causal: only tiles with kv0 <= q0+64
  for (int kv0 = 0; kv0 < kv_end; kv0 += 64) {
    __syncthreads();   // previous tile's LDS reads done before overwrite

    // ---- stage K tile: fp32 global -> bf16 LDS, row-major, coalesced ----
    #pragma unroll
    for (int i = 0; i < 4; ++i) {
      const int idx = i * 256 + tid;        // 0..1023 chunks of 8 floats
      const int kr  = idx >> 4;             // kv row 0..63
      const int dc  = (idx & 15) * 8;       // d 0..120
      const float* src = Kb + (size_t)(kv0 + kr) * 128 + dc;
      f32x4 a = *(const f32x4*)src;
      f32x4 b = *(const f32x4*)(src + 4);
      bf16x8 w;
      #pragma unroll
      for (int j = 0; j < 4; ++j) { w[j] = f2bf(a[j]); w[4 + j] = f2bf(b[j]); }
      *(bf16x8*)&K_lds[kr * KLD + dc] = w;
    }
    // ---- stage V tile transposed: V_T[d][kv], pair-packed b32 writes ----
    {
      const int d   = tid & 31;
      const int prb = tid >> 5;
      #pragma unroll
      for (int i = 0; i < 4; ++i) {
        const int pr = prb + i * 8;         // kv pair 0..31
        const float* v0 = Vb + (size_t)(kv0 + 2 * pr) * 128 + d;
        #pragma unroll
        for (int j = 0; j < 4; ++j) {
          const float f0 = v0[j * 32];
          const float f1 = v0[j * 32 + 128];
          const unsigned pk = (unsigned)(unsigned short)f2bf(f0)
                            | ((unsigned)(unsigned short)f2bf(f1) << 16);
          *(unsigned*)&V_T[(d + j * 32) * VLD + 2 * pr] = pk;
        }
      }
    }
    __syncthreads();

    // wave fully above the causal boundary for this tile -> no contribution
    if (kv0 > q0 + wave * 32 + 31) continue;

    // ---- QK^T: S[2][4] tiles, B-frag from K_lds (col=lo is kv col) ----
    f32x4 s[2][4];
    #pragma unroll
    for (int mt = 0; mt < 2; ++mt)
      #pragma unroll
      for (int nb = 0; nb < 4; ++nb) s[mt][nb] = (f32x4){0.f, 0.f, 0.f, 0.f};

    #pragma unroll
    for (int nb = 0; nb < 4; ++nb) {
      #pragma unroll
      for (int kb = 0; kb < 4; ++kb) {
        bf16x8 bk = *(const bf16x8*)&K_lds[(nb * 16 + lo) * KLD + kb * 32 + g * 8];
        s[0][nb] = __builtin_amdgcn_mfma_f32_16x16x32_bf16(qf[0][kb], bk, s[0][nb], 0, 0, 0);
        s[1][nb] = __builtin_amdgcn_mfma_f32_16x16x32_bf16(qf[1][kb], bk, s[1][nb], 0, 0, 0);
      }
    }

    // ---- causal mask (only tiles touching the diagonal for this wave) ----
    if (kv0 + 63 > q0 + wave * 32) {
      #pragma unroll
      for (int mt = 0; mt < 2; ++mt) {
        const int rowb = q0 + wave * 32 + mt * 16 + g * 4;
        #pragma unroll
        for (int nb = 0; nb < 4; ++nb) {
          const int col = kv0 + nb * 16 + lo;
          #pragma unroll
          for (int r = 0; r < 4; ++r)
            if (col > rowb + r) s[mt][nb][r] = -1.0e30f;
        }
      }
    }

    // ---- online softmax (rows live as (g,r); reduce across 16 lanes) ----
    #pragma unroll
    for (int mt = 0; mt < 2; ++mt) {
      float tm[4], alpha[4], psum[4];
      #pragma unroll
      for (int r = 0; r < 4; ++r)
        tm[r] = fmaxf(fmaxf(s[mt][0][r], s[mt][1][r]), fmaxf(s[mt][2][r], s[mt][3][r]));
      #pragma unroll
      for (int off = 1; off < 16; off <<= 1)
        #pragma unroll
        for (int r = 0; r < 4; ++r)
          tm[r] = fmaxf(tm[r], __shfl_xor(tm[r], off));
      #pragma unroll
      for (int r = 0; r < 4; ++r) {
        const float mn = fmaxf(m_st[mt][r], tm[r]);
        alpha[r] = __builtin_amdgcn_exp2f((m_st[mt][r] - mn) * LOG2E);
        m_st[mt][r] = mn;
        psum[r] = 0.0f;
      }
      #pragma unroll
      for (int nb = 0; nb < 4; ++nb) {
        #pragma unroll
        for (int r = 0; r < 4; ++r) {
          const float p = __builtin_amdgcn_exp2f((s[mt][nb][r] - m_st[mt][r]) * LOG2E);
          psum[r] += p;
          Pw[(mt * 16 + g * 4 + r) * PLD + nb * 16 + lo] = f2bf(p);
        }
      }
      #pragma unroll
      for (int off = 1; off < 16; off <<= 1)
        #pragma unroll
        for (int r = 0; r < 4; ++r)
          psum[r] += __shfl_xor(psum[r], off);
      #pragma unroll
      for (int r = 0; r < 4; ++r)
        l_st[mt][r] = l_st[mt][r] * alpha[r] + psum[r];
      #pragma unroll
      for (int nb = 0; nb < 8; ++nb)
        #pragma unroll
        for (int r = 0; r < 4; ++r)
          o_acc[mt][nb][r] *= alpha[r];
    }

    // ---- PV: A-frag = P from LDS (row=lo), B-frag = V_T (contiguous kv) ----
    #pragma unroll
    for (int kb2 = 0; kb2 < 2; ++kb2) {
      bf16x8 pa0 = *(const bf16x8*)&Pw[lo * PLD + kb2 * 32 + g * 8];
      bf16x8 pa1 = *(const bf16x8*)&Pw[(16 + lo) * PLD + kb2 * 32 + g * 8];
      #pragma unroll
      for (int nb = 0; nb < 8; ++nb) {
        bf16x8 bv = *(const bf16x8*)&V_T[(nb * 16 + lo) * VLD + kb2 * 32 + g * 8];
        o_acc[0][nb] = __builtin_amdgcn_mfma_f32_16x16x32_bf16(pa0, bv, o_acc[0][nb], 0, 0, 0);
        o_acc[1][nb] = __builtin_amdgcn_mfma_f32_16x16x32_bf16(pa1, bv, o_acc[1][nb], 0, 0, 0);
      }
    }
  }

  // ---- epilogue: O = o_acc / l ----
  #pragma unroll
  for (int mt = 0; mt < 2; ++mt) {
    #pragma unroll
    for (int r = 0; r < 4; ++r) {
      const float inv = 1.0f / l_st[mt][r];
      float* orow = Ob + (size_t)(q0 + wave * 32 + mt * 16 + g * 4 + r) * 128 + lo;
      #pragma unroll
      for (int nb = 0; nb < 8; ++nb)
        orow[nb * 16] = o_acc[mt][nb][r] * inv;
    }
  }
}

extern "C" void kernel_launch(void* const* d_in, const int* in_sizes, int n_in,
                              void* d_out, int out_size, void* d_ws, size_t ws_size,
                              hipStream_t stream) {
  const float* Q = (const float*)d_in[0];
  const float* K = (const float*)d_in[1];
  const float* V = (const float*)d_in[2];
  float* O = (float*)d_out;
  // B*H = 64 heads (x, fastest -> balances causal work across CUs), 16 q-tiles (y)
  dim3 grid(64, 16);
  attn_fwd<<<grid, 256, 0, stream>>>(Q, K, V, O);
}